// Round 2
// baseline (81769.214 us; speedup 1.0000x reference)
//
#include <hip/hip_runtime.h>
#include <math.h>

#define NB   32      // batch
#define NPF  100
#define FIN  36
#define FC   40
#define KSEL 11
#define HH   3600
#define EPSB 0.001
#define ETA_C 12
#define PHI_C 13
#define KC   240     // k-chunk staged in LDS per iteration
#define CPAD 34      // padded LDS row stride (even -> aligned double2)

// ---------------------------------------------------------------------------
// Preprocess (f64): embeddings + normalization -> x[32][100][40] doubles
// ---------------------------------------------------------------------------
__global__ __launch_bounds__(256) void pre_kernel(
    const float* __restrict__ xx, const float* __restrict__ emb1,
    const float* __restrict__ emb2, const float* __restrict__ emb3,
    const float* __restrict__ mean, const float* __restrict__ std_,
    const float* __restrict__ vmin, const float* __restrict__ vmax,
    double* __restrict__ x)
{
    int b = blockIdx.x;
    for (int t = threadIdx.x; t < NPF * FC; t += 256) {
        int p = t / FC, c = t % FC;
        const float* row = xx + (size_t)(b * NPF + p) * FIN;
        double v;
        if (c < 2) {
            int idx = (int)fabsf(row[0]);
            v = (double)emb1[2 * idx + c];
        } else if (c < 4) {
            int idx = (int)fabsf(row[1]);
            v = (double)emb2[2 * idx + (c - 2)];
        } else if (c < 6) {
            int idx = (int)fabsf(row[2]);
            v = (double)emb3[2 * idx + (c - 4)];
        } else {
            int f = c - 4;                  // c=6 -> feature 2
            v = (double)row[f];
            if (f >= 3) {
                double y = fmin(fmax((v - (double)mean[f]) / (double)std_[f], -5.0), 5.0);
                double sc = 2.0 / ((double)vmax[f] - (double)vmin[f]);
                v = fmin(fmax(sc * (y - (double)vmin[f]) - 1.0, -1.0), 1.0);
            }
        }
        x[(size_t)(b * NPF + p) * FC + c] = v;
    }
}

// ---------------------------------------------------------------------------
// KNN (f64): c2 = bnrelu(sum 2 partials + bias) @ Wc + bc (or ref0 if first),
// distances, stable top-11, gather g[32][440]
// ---------------------------------------------------------------------------
__global__ __launch_bounds__(256) void knn_kernel(
    const double* __restrict__ x, const double* __restrict__ hparts,
    const float* __restrict__ bias, const float* __restrict__ gam,
    const float* __restrict__ bet, const float* __restrict__ mm,
    const float* __restrict__ mv, const float* __restrict__ Wc,
    const float* __restrict__ bc, double* __restrict__ g_out, int first)
{
    int b = blockIdx.x, tid = threadIdx.x;
    __shared__ double sd[NPF];
    __shared__ int    sel[KSEL];
    __shared__ double sc2[2];
    __shared__ double red[8];

    double c2x, c2y;
    if (first) {
        c2x = x[(size_t)(b * NPF) * FC + ETA_C];
        c2y = x[(size_t)(b * NPF) * FC + PHI_C];
    } else {
        double ax = 0.0, ay = 0.0;
        for (int j = tid; j < HH; j += 256) {
            double v = hparts[(size_t)b * HH + j]
                     + hparts[(size_t)NB * HH + (size_t)b * HH + j];
            v += (double)bias[j];
            v = (double)gam[j] * (v - (double)mm[j]) * (1.0 / sqrt((double)mv[j] + EPSB))
              + (double)bet[j];
            v = fmax(v, 0.0);
            ax += v * (double)Wc[2 * j];
            ay += v * (double)Wc[2 * j + 1];
        }
        for (int o = 32; o >= 1; o >>= 1) {
            ax += __shfl_xor(ax, o);
            ay += __shfl_xor(ay, o);
        }
        int wv = tid >> 6;
        if ((tid & 63) == 0) { red[wv * 2] = ax; red[wv * 2 + 1] = ay; }
        __syncthreads();
        if (tid == 0) {
            sc2[0] = red[0] + red[2] + red[4] + red[6] + (double)bc[0];
            sc2[1] = red[1] + red[3] + red[5] + red[7] + (double)bc[1];
        }
        __syncthreads();
        c2x = sc2[0]; c2y = sc2[1];
    }
    if (tid < NPF) {
        double dx = x[(size_t)(b * NPF + tid) * FC + ETA_C] - c2x;
        double dy = x[(size_t)(b * NPF + tid) * FC + PHI_C] - c2y;
        sd[tid] = sqrt(dx * dx + dy * dy);
    }
    __syncthreads();
    if (tid < NPF) {
        double dp = sd[tid];
        int cnt = 0;
        for (int q = 0; q < NPF; ++q) {
            double dq = sd[q];
            cnt += (dq < dp) || (dq == dp && q < tid);  // stable top-k order
        }
        if (cnt < KSEL) sel[cnt] = tid;
    }
    __syncthreads();
    for (int t = tid; t < KSEL * FC; t += 256) {
        int kk = t / FC, f = t % FC;
        g_out[(size_t)b * (KSEL * FC) + t] = x[(size_t)(b * NPF + sel[kk]) * FC + f];
    }
}

// ---------------------------------------------------------------------------
// GEMM (f64 accumulate): Pout[sk][32][3600] = stage(A) @ W
// stage = sum sk_in partial slots + bias + BN + ReLU (skipped if bias==null).
// block: 256 thr = 16 colgroups x 16 kslices; 2 cols/thread; 32-row acc.
// grid: (113, SK); block y owns k range [y*KRC, y*KRC+KRC), guarded vs KA.
// ---------------------------------------------------------------------------
__global__ __launch_bounds__(256) void gemm_kernel(
    const double* __restrict__ Ain, int sk_in, int KA, int slotStride,
    const float* __restrict__ bias, const float* __restrict__ gam,
    const float* __restrict__ bet, const float* __restrict__ mm,
    const float* __restrict__ mv, const float* __restrict__ W,
    double* __restrict__ Pout, int KRC)
{
    __shared__ double As[KC * CPAD];   // 240*34*8 = 65280 B
    const int tid = threadIdx.x;
    const int g = tid & 15, s = tid >> 4;
    int c0 = blockIdx.x * 32 + g * 2;
    if (c0 > HH - 2) c0 = HH - 2;          // clamp; duplicate stores identical
    const int k0 = blockIdx.y * KRC;
    const bool do_bn = (bias != nullptr);

    double acc[32][2];
#pragma unroll
    for (int r = 0; r < 32; ++r) { acc[r][0] = 0.0; acc[r][1] = 0.0; }

    for (int kc = 0; kc < KRC; kc += KC) {
        const int kbase = k0 + kc;
        if (kbase >= KA) break;            // uniform across block
        __syncthreads();
        // ---- stage A chunk transposed into LDS (sum partials + bn + relu) ----
        for (int t = tid; t < (32 * KC / 2); t += 256) {
            int r = t & 31;
            int q = t >> 5;                // double2 index along k, 0..119
            int kg = kbase + 2 * q;
            double v0 = 0.0, v1 = 0.0;
            if (kg < KA) {
                const double* ap = Ain + (size_t)r * KA + kg;
                double2 u = *(const double2*)ap;
                v0 = u.x; v1 = u.y;
                for (int s2 = 1; s2 < sk_in; ++s2) {
                    double2 w = *(const double2*)(ap + (size_t)s2 * slotStride);
                    v0 += w.x; v1 += w.y;
                }
                if (do_bn) {
                    float2 bb = *(const float2*)(bias + kg);
                    float2 gg = *(const float2*)(gam + kg);
                    float2 be = *(const float2*)(bet + kg);
                    float2 m1 = *(const float2*)(mm + kg);
                    float2 m2 = *(const float2*)(mv + kg);
                    v0 = fmax((double)gg.x * ((v0 + (double)bb.x) - (double)m1.x)
                              * (1.0 / sqrt((double)m2.x + EPSB)) + (double)be.x, 0.0);
                    v1 = fmax((double)gg.y * ((v1 + (double)bb.y) - (double)m1.y)
                              * (1.0 / sqrt((double)m2.y + EPSB)) + (double)be.y, 0.0);
                }
            }
            As[(2 * q) * CPAD + r]     = v0;
            As[(2 * q + 1) * CPAD + r] = v1;
        }
        __syncthreads();
        // ---- inner product: each thread covers k = kbase + s + 16*i ----
#pragma unroll 2
        for (int i = 0; i < KC / 16; ++i) {
            const int kl = s + 16 * i;
            const int kg = kbase + kl;
            double wx = 0.0, wy = 0.0;
            if (kg < KA) {
                float2 wv = *(const float2*)(W + (size_t)kg * HH + c0);
                wx = (double)wv.x; wy = (double)wv.y;
            }
            const double* as = &As[kl * CPAD];
#pragma unroll
            for (int r2 = 0; r2 < 16; ++r2) {
                double2 a = *(const double2*)(as + 2 * r2);
                acc[2 * r2 + 0][0] += a.x * wx; acc[2 * r2 + 0][1] += a.x * wy;
                acc[2 * r2 + 1][0] += a.y * wx; acc[2 * r2 + 1][1] += a.y * wy;
            }
        }
    }
    // ---- reduce 16 kslices: 4 within wave via shuffles, 4 waves via LDS ----
#pragma unroll
    for (int r = 0; r < 32; ++r) {
        acc[r][0] += __shfl_xor(acc[r][0], 16);
        acc[r][0] += __shfl_xor(acc[r][0], 32);
        acc[r][1] += __shfl_xor(acc[r][1], 16);
        acc[r][1] += __shfl_xor(acc[r][1], 32);
    }
    __syncthreads();
    const int wv = tid >> 6, lane = tid & 63;
    if (wv > 0 && lane < 16) {
        double* dst = &As[((wv - 1) * 16 + g) * 64];
#pragma unroll
        for (int r = 0; r < 32; ++r) { dst[r * 2] = acc[r][0]; dst[r * 2 + 1] = acc[r][1]; }
    }
    __syncthreads();
    if (tid < 16) {
        double* outp = Pout + (size_t)blockIdx.y * (NB * HH);
#pragma unroll
        for (int r = 0; r < 32; ++r) {
            double v0 = acc[r][0], v1 = acc[r][1];
            for (int w2 = 0; w2 < 3; ++w2) {
                v0 += As[(w2 * 16 + g) * 64 + r * 2];
                v1 += As[(w2 * 16 + g) * 64 + r * 2 + 1];
            }
            *(double2*)(outp + (size_t)r * HH + c0) = make_double2(v0, v1);
        }
    }
}

// ---------------------------------------------------------------------------
// Head (f64): h -> x2, softmax(h@W100+b100), weighted sums, physics -> out[32][6]
// ---------------------------------------------------------------------------
__global__ __launch_bounds__(256) void head_kernel(
    const float* __restrict__ xx, const double* __restrict__ hparts,
    const float* __restrict__ bias, const float* __restrict__ gam,
    const float* __restrict__ bet, const float* __restrict__ mm,
    const float* __restrict__ mv, const float* __restrict__ W2,
    const float* __restrict__ b2, const float* __restrict__ W100,
    const float* __restrict__ b100, float* __restrict__ out)
{
    int b = blockIdx.x, tid = threadIdx.x;
    __shared__ double hs[HH];
    __shared__ double buf[NPF];
    __shared__ double red[8];
    __shared__ double acc4[4 * NPF];
    __shared__ double sstat[2];

    for (int j = tid; j < HH; j += 256) {
        double v = hparts[(size_t)b * HH + j]
                 + hparts[(size_t)NB * HH + (size_t)b * HH + j];
        v += (double)bias[j];
        v = (double)gam[j] * (v - (double)mm[j]) * (1.0 / sqrt((double)mv[j] + EPSB))
          + (double)bet[j];
        hs[j] = fmax(v, 0.0);
    }
    __syncthreads();
    // x2 = h @ W2 + b2
    double a0 = 0.0, a1 = 0.0;
    for (int j = tid; j < HH; j += 256) {
        a0 += hs[j] * (double)W2[2 * j];
        a1 += hs[j] * (double)W2[2 * j + 1];
    }
    for (int o = 32; o >= 1; o >>= 1) { a0 += __shfl_xor(a0, o); a1 += __shfl_xor(a1, o); }
    if ((tid & 63) == 0) { red[(tid >> 6) * 2] = a0; red[(tid >> 6) * 2 + 1] = a1; }
    // logits: 2 threads per output column
    double lg = 0.0;
    int p = tid >> 1, half = tid & 1;
    if (tid < 2 * NPF) {
        for (int j = half * (HH / 2); j < (half + 1) * (HH / 2); ++j)
            lg += hs[j] * (double)W100[(size_t)j * NPF + p];
    }
    lg += __shfl_xor(lg, 1);
    __syncthreads();
    if (tid < 2 * NPF && half == 0) buf[p] = lg + (double)b100[p];
    __syncthreads();
    if (tid == 0) {
        double m = buf[0];
        for (int q = 1; q < NPF; ++q) m = fmax(m, buf[q]);
        sstat[0] = m;
    }
    __syncthreads();
    if (tid < NPF) buf[tid] = exp(buf[tid] - sstat[0]);
    __syncthreads();
    if (tid == 0) {
        double sm = 0.0;
        for (int q = 0; q < NPF; ++q) sm += buf[q];
        sstat[1] = sm;
    }
    __syncthreads();
    if (tid < NPF) {
        const float* row = xx + (size_t)(b * NPF + tid) * FIN;
        double w = buf[tid] / sstat[1] * (double)row[7];
        acc4[tid]            = (double)row[3] * w;
        acc4[NPF + tid]      = (double)row[4] * w;
        acc4[2 * NPF + tid]  = (double)row[5] * w;
        acc4[3 * NPF + tid]  = (double)row[6] * w;
    }
    __syncthreads();
    if (tid == 0) {
        double px = 0.0, py = 0.0, pz = 0.0, E = 0.0;
        for (int q = 0; q < NPF; ++q) {
            px += acc4[q]; py += acc4[NPF + q]; pz += acc4[2 * NPF + q]; E += acc4[3 * NPF + q];
        }
        double x2_0 = red[0] + red[2] + red[4] + red[6] + (double)b2[0];
        double x2_1 = red[1] + red[3] + red[5] + red[7] + (double)b2[1];
        double px2 = px * px, py2 = py * py, pz2 = pz * pz;
        double pt = sqrt(px2 + py2);
        double mass2 = E * E - px2 - py2 - pz2;
        double absp = sqrt(px2 + py2 + pz2);
        double cosT = (absp == 0.0) ? 1.0 : pz / absp;
        bool ok = cosT * cosT < 1.0;
        double ratio = ok ? (1.0 - cosT) / (1.0 + cosT) : 1.0;
        double eta = ok ? -0.5 * log(ratio) : 0.0;
        double phi = (px == 0.0 && py == 0.0) ? 0.0 : atan2(py, px);
        out[b * 6 + 0] = (float)x2_0; out[b * 6 + 1] = (float)x2_1; out[b * 6 + 2] = (float)pt;
        out[b * 6 + 3] = (float)eta;  out[b * 6 + 4] = (float)phi;  out[b * 6 + 5] = (float)mass2;
    }
}

// ---------------------------------------------------------------------------
extern "C" void kernel_launch(void* const* d_in, const int* in_sizes, int n_in,
                              void* d_out, int out_size, void* d_ws, size_t ws_size,
                              hipStream_t stream)
{
    const float* xx    = (const float*)d_in[0];
    const float* emb1  = (const float*)d_in[1];
    const float* emb2  = (const float*)d_in[2];
    const float* emb3  = (const float*)d_in[3];
    const float* mean  = (const float*)d_in[4];
    const float* std_  = (const float*)d_in[5];
    const float* vmin  = (const float*)d_in[6];
    const float* vmax  = (const float*)d_in[7];
    const float* W0    = (const float*)d_in[8];
    const float* b0    = (const float*)d_in[9];
    const float* Wh    = (const float*)d_in[10];
    const float* bh    = (const float*)d_in[11];
    const float* gamma = (const float*)d_in[12];
    const float* beta  = (const float*)d_in[13];
    const float* mmean = (const float*)d_in[14];
    const float* mvar  = (const float*)d_in[15];
    const float* Wc    = (const float*)d_in[16];
    const float* bc    = (const float*)d_in[17];
    const float* W2    = (const float*)d_in[18];
    const float* b2    = (const float*)d_in[19];
    const float* W100  = (const float*)d_in[20];
    const float* b100  = (const float*)d_in[21];

    double* ws   = (double*)d_ws;
    double* x    = ws;                       // 128000 d
    double* gbuf = x + 32 * 100 * 40;        // 14080 d
    double* Pa   = gbuf + 32 * 440;          // 2*32*3600 = 230400 d
    double* Pb   = Pa + 2 * NB * HH;
    double* Ph   = Pb + 2 * NB * HH;         // total ~6.7 MB

    const size_t HS = (size_t)HH;

    pre_kernel<<<dim3(NB), dim3(256), 0, stream>>>(xx, emb1, emb2, emb3, mean, std_, vmin, vmax, x);

    for (int t = 0; t < NPF; ++t) {
        knn_kernel<<<dim3(NB), dim3(256), 0, stream>>>(
            x, Ph, bh + 3 * HS, gamma + 4 * HS, beta + 4 * HS, mmean + 4 * HS, mvar + 4 * HS,
            Wc, bc, gbuf, (t == 0) ? 1 : 0);
        // L0: g[32,440] @ W0 -> Pa slot0 (raw)
        gemm_kernel<<<dim3(113, 1), dim3(256), 0, stream>>>(
            gbuf, 1, 440, 0, nullptr, nullptr, nullptr, nullptr, nullptr, W0, Pa, 480);
        // L1: bnrelu(Pa+b0, bn0) @ Wh[0] -> Pb (2 partials)
        gemm_kernel<<<dim3(113, 2), dim3(256), 0, stream>>>(
            Pa, 1, HH, NB * HH, b0, gamma, beta, mmean, mvar, Wh, Pb, 1920);
        // L2: bnrelu(Pb+bh0, bn1) @ Wh[1] -> Pa
        gemm_kernel<<<dim3(113, 2), dim3(256), 0, stream>>>(
            Pb, 2, HH, NB * HH, bh, gamma + HS, beta + HS, mmean + HS, mvar + HS,
            Wh + HS * HS, Pa, 1920);
        // L3: bnrelu(Pa+bh1, bn2) @ Wh[2] -> Pb
        gemm_kernel<<<dim3(113, 2), dim3(256), 0, stream>>>(
            Pa, 2, HH, NB * HH, bh + HS, gamma + 2 * HS, beta + 2 * HS, mmean + 2 * HS,
            mvar + 2 * HS, Wh + 2 * HS * HS, Pb, 1920);
        // L4: bnrelu(Pb+bh2, bn3) @ Wh[3] -> Ph
        gemm_kernel<<<dim3(113, 2), dim3(256), 0, stream>>>(
            Pb, 2, HH, NB * HH, bh + 2 * HS, gamma + 3 * HS, beta + 3 * HS, mmean + 3 * HS,
            mvar + 3 * HS, Wh + 3 * HS * HS, Ph, 1920);
    }
    head_kernel<<<dim3(NB), dim3(256), 0, stream>>>(
        xx, Ph, bh + 3 * HS, gamma + 4 * HS, beta + 4 * HS, mmean + 4 * HS, mvar + 4 * HS,
        W2, b2, W100, b100, (float*)d_out);
}

// Round 3
// 37990.564 us; speedup vs baseline: 2.1524x; 2.1524x over previous
//
#include <hip/hip_runtime.h>
#include <math.h>

#define NB   32      // batch (= GEMM M)
#define NPF  100
#define FIN  36
#define FC   40
#define KSEL 11
#define HH   3600
#define EPSB 0.001
#define ETA_C 12
#define PHI_C 13
#define MROWS 32
#define PSTRIDE (MROWS * HH)   // one split-K partial slot: 115200 doubles
#define SKH  17                // hidden split-K (grid 15x17 = 255 blocks ~ 1/CU)
#define KRCH 212               // 17*212 = 3604 >= 3600
#define SK0  16                // L0 split-K
#define KRC0 28                // 16*28 = 448 >= 440

// ---------------------------------------------------------------------------
// Preprocess (f64): embeddings + normalization -> x[32][100][40]
// ---------------------------------------------------------------------------
__global__ __launch_bounds__(256) void pre_kernel(
    const float* __restrict__ xx, const float* __restrict__ emb1,
    const float* __restrict__ emb2, const float* __restrict__ emb3,
    const float* __restrict__ mean, const float* __restrict__ std_,
    const float* __restrict__ vmin, const float* __restrict__ vmax,
    double* __restrict__ x)
{
    int b = blockIdx.x;
    for (int t = threadIdx.x; t < NPF * FC; t += 256) {
        int p = t / FC, c = t % FC;
        const float* row = xx + (size_t)(b * NPF + p) * FIN;
        double v;
        if (c < 2) {
            int idx = (int)fabsf(row[0]);
            v = (double)emb1[2 * idx + c];
        } else if (c < 4) {
            int idx = (int)fabsf(row[1]);
            v = (double)emb2[2 * idx + (c - 2)];
        } else if (c < 6) {
            int idx = (int)fabsf(row[2]);
            v = (double)emb3[2 * idx + (c - 4)];
        } else {
            int f = c - 4;                  // c=6 -> feature 2
            v = (double)row[f];
            if (f >= 3) {
                double y = fmin(fmax((v - (double)mean[f]) / (double)std_[f], -5.0), 5.0);
                double sc = 2.0 / ((double)vmax[f] - (double)vmin[f]);
                v = fmin(fmax(sc * (y - (double)vmin[f]) - 1.0, -1.0), 1.0);
            }
        }
        x[(size_t)(b * NPF + p) * FC + c] = v;
    }
}

// ---------------------------------------------------------------------------
// GEMM (f64): P[slot by][32][3600] = A[k0:kend][32]^T-slice @ W[k][3600]
// A is k-major [KA][32] so a k-column is wave-uniform -> scalar loads.
// Block 256 thr: waves 0-1 rows 0-15 / waves 2-3 rows 16-31 (W re-read L1-hit);
// each thread 2 contiguous cols. Per thread: acc[16][2] f64 (64 VGPR),
// 32 independent FMA chains -> saturates f64 pipe at 1 wave/SIMD.
// ---------------------------------------------------------------------------
__global__ __launch_bounds__(256) void gemm_kernel(
    const double* __restrict__ A, const float* __restrict__ W,
    double* __restrict__ P, int KA, int KRC)
{
    const int tid = threadIdx.x;
    const int rg = __builtin_amdgcn_readfirstlane(tid >> 7);  // wave-uniform rowgroup
    const int lh = tid & 127;
    const int j0 = blockIdx.x * 256 + lh * 2;
    const bool jok = (j0 < HH);
    const int jc = jok ? j0 : (HH - 2);     // clamp for tail-block loads
    const int k0 = blockIdx.y * KRC;
    const int kend = min(k0 + KRC, KA);

    double acc[16][2];
#pragma unroll
    for (int r = 0; r < 16; ++r) { acc[r][0] = 0.0; acc[r][1] = 0.0; }

    const double* __restrict__ Ap = A + (size_t)k0 * MROWS + rg * 16;
    const float* __restrict__ Wp = W + (size_t)k0 * HH + jc;

#pragma unroll 2
    for (int k = k0; k < kend; ++k) {
        float2 wv = *(const float2*)Wp;
        double w0 = (double)wv.x, w1 = (double)wv.y;
#pragma unroll
        for (int r = 0; r < 16; ++r) {
            double a = Ap[r];               // uniform address -> s_load
            acc[r][0] = fma(a, w0, acc[r][0]);
            acc[r][1] = fma(a, w1, acc[r][1]);
        }
        Ap += MROWS;
        Wp += HH;
    }
    if (jok) {
        double* op = P + (size_t)blockIdx.y * PSTRIDE + (size_t)(rg * 16) * HH + j0;
#pragma unroll
        for (int r = 0; r < 16; ++r)
            *(double2*)(op + (size_t)r * HH) = make_double2(acc[r][0], acc[r][1]);
    }
}

// ---------------------------------------------------------------------------
// Fixup: sum nslot partial slots + bias + BN + ReLU -> Aout[k=out-col][32 rows]
// (transposed k-major layout for the next GEMM's scalar loads).
// Block 256 = 32 rows x 8 cols; grid 450 (450*8 = 3600).
// ---------------------------------------------------------------------------
__global__ __launch_bounds__(256) void fix_kernel(
    const double* __restrict__ P, int nslot,
    const float* __restrict__ bias, const float* __restrict__ gam,
    const float* __restrict__ bet, const float* __restrict__ mm,
    const float* __restrict__ mv, double* __restrict__ Aout)
{
    __shared__ double t[8][33];
    const int tid = threadIdx.x;
    const int r = tid >> 3, jj = tid & 7;
    const int j = blockIdx.x * 8 + jj;
    const double* p = P + (size_t)r * HH + j;
    double s = 0.0;
    for (int sl = 0; sl < nslot; ++sl) s += p[(size_t)sl * PSTRIDE];
    s += (double)bias[j];
    s = (double)gam[j] * (s - (double)mm[j]) * (1.0 / sqrt((double)mv[j] + EPSB))
      + (double)bet[j];
    t[jj][r] = fmax(s, 0.0);
    __syncthreads();
    const int jj2 = tid >> 5, r2 = tid & 31;
    Aout[(size_t)(blockIdx.x * 8 + jj2) * MROWS + r2] = t[jj2][r2];
}

// ---------------------------------------------------------------------------
// KNN (f64): c2 = act^T @ Wc + bc (act already bn4+relu'd, k-major [3600][32]),
// distances, stable top-11, gather g^T [440][32] (k-major for L0 scalar loads)
// ---------------------------------------------------------------------------
__global__ __launch_bounds__(256) void knn_kernel(
    const double* __restrict__ x, const double* __restrict__ act,
    const float* __restrict__ Wc, const float* __restrict__ bc,
    double* __restrict__ g_out, int first)
{
    int b = blockIdx.x, tid = threadIdx.x;
    __shared__ double sd[NPF];
    __shared__ int    sel[KSEL];
    __shared__ double sc2[2];
    __shared__ double red[8];

    double c2x, c2y;
    if (first) {
        c2x = x[(size_t)(b * NPF) * FC + ETA_C];
        c2y = x[(size_t)(b * NPF) * FC + PHI_C];
    } else {
        double ax = 0.0, ay = 0.0;
        for (int j = tid; j < HH; j += 256) {
            double v = act[(size_t)j * MROWS + b];
            ax += v * (double)Wc[2 * j];
            ay += v * (double)Wc[2 * j + 1];
        }
        for (int o = 32; o >= 1; o >>= 1) {
            ax += __shfl_xor(ax, o);
            ay += __shfl_xor(ay, o);
        }
        int wv = tid >> 6;
        if ((tid & 63) == 0) { red[wv * 2] = ax; red[wv * 2 + 1] = ay; }
        __syncthreads();
        if (tid == 0) {
            sc2[0] = red[0] + red[2] + red[4] + red[6] + (double)bc[0];
            sc2[1] = red[1] + red[3] + red[5] + red[7] + (double)bc[1];
        }
        __syncthreads();
        c2x = sc2[0]; c2y = sc2[1];
    }
    if (tid < NPF) {
        double dx = x[(size_t)(b * NPF + tid) * FC + ETA_C] - c2x;
        double dy = x[(size_t)(b * NPF + tid) * FC + PHI_C] - c2y;
        sd[tid] = sqrt(dx * dx + dy * dy);
    }
    __syncthreads();
    if (tid < NPF) {
        double dp = sd[tid];
        int cnt = 0;
        for (int q = 0; q < NPF; ++q) {
            double dq = sd[q];
            cnt += (dq < dp) || (dq == dp && q < tid);  // stable top-k order
        }
        if (cnt < KSEL) sel[cnt] = tid;
    }
    __syncthreads();
    for (int t = tid; t < KSEL * FC; t += 256) {
        int kk = t / FC, f = t % FC;
        g_out[(size_t)t * MROWS + b] = x[(size_t)(b * NPF + sel[kk]) * FC + f];
    }
}

// ---------------------------------------------------------------------------
// Head (f64): act (pre-activated) -> x2, softmax, weighted sums -> out[32][6]
// ---------------------------------------------------------------------------
__global__ __launch_bounds__(256) void head_kernel(
    const float* __restrict__ xx, const double* __restrict__ act,
    const float* __restrict__ W2, const float* __restrict__ b2,
    const float* __restrict__ W100, const float* __restrict__ b100,
    float* __restrict__ out)
{
    int b = blockIdx.x, tid = threadIdx.x;
    __shared__ double hs[HH];
    __shared__ double buf[NPF];
    __shared__ double red[8];
    __shared__ double acc4[4 * NPF];
    __shared__ double sstat[2];

    for (int j = tid; j < HH; j += 256) hs[j] = act[(size_t)j * MROWS + b];
    __syncthreads();
    double a0 = 0.0, a1 = 0.0;
    for (int j = tid; j < HH; j += 256) {
        a0 += hs[j] * (double)W2[2 * j];
        a1 += hs[j] * (double)W2[2 * j + 1];
    }
    for (int o = 32; o >= 1; o >>= 1) { a0 += __shfl_xor(a0, o); a1 += __shfl_xor(a1, o); }
    if ((tid & 63) == 0) { red[(tid >> 6) * 2] = a0; red[(tid >> 6) * 2 + 1] = a1; }
    double lg = 0.0;
    int p = tid >> 1, half = tid & 1;
    if (tid < 2 * NPF) {
        for (int j = half * (HH / 2); j < (half + 1) * (HH / 2); ++j)
            lg += hs[j] * (double)W100[(size_t)j * NPF + p];
    }
    lg += __shfl_xor(lg, 1);
    __syncthreads();
    if (tid < 2 * NPF && half == 0) buf[p] = lg + (double)b100[p];
    __syncthreads();
    if (tid == 0) {
        double m = buf[0];
        for (int q = 1; q < NPF; ++q) m = fmax(m, buf[q]);
        sstat[0] = m;
    }
    __syncthreads();
    if (tid < NPF) buf[tid] = exp(buf[tid] - sstat[0]);
    __syncthreads();
    if (tid == 0) {
        double sm = 0.0;
        for (int q = 0; q < NPF; ++q) sm += buf[q];
        sstat[1] = sm;
    }
    __syncthreads();
    if (tid < NPF) {
        const float* row = xx + (size_t)(b * NPF + tid) * FIN;
        double w = buf[tid] / sstat[1] * (double)row[7];
        acc4[tid]           = (double)row[3] * w;
        acc4[NPF + tid]     = (double)row[4] * w;
        acc4[2 * NPF + tid] = (double)row[5] * w;
        acc4[3 * NPF + tid] = (double)row[6] * w;
    }
    __syncthreads();
    if (tid == 0) {
        double px = 0.0, py = 0.0, pz = 0.0, E = 0.0;
        for (int q = 0; q < NPF; ++q) {
            px += acc4[q]; py += acc4[NPF + q]; pz += acc4[2 * NPF + q]; E += acc4[3 * NPF + q];
        }
        double x2_0 = red[0] + red[2] + red[4] + red[6] + (double)b2[0];
        double x2_1 = red[1] + red[3] + red[5] + red[7] + (double)b2[1];
        double px2 = px * px, py2 = py * py, pz2 = pz * pz;
        double pt = sqrt(px2 + py2);
        double mass2 = E * E - px2 - py2 - pz2;
        double absp = sqrt(px2 + py2 + pz2);
        double cosT = (absp == 0.0) ? 1.0 : pz / absp;
        bool ok = cosT * cosT < 1.0;
        double ratio = ok ? (1.0 - cosT) / (1.0 + cosT) : 1.0;
        double eta = ok ? -0.5 * log(ratio) : 0.0;
        double phi = (px == 0.0 && py == 0.0) ? 0.0 : atan2(py, px);
        out[b * 6 + 0] = (float)x2_0; out[b * 6 + 1] = (float)x2_1; out[b * 6 + 2] = (float)pt;
        out[b * 6 + 3] = (float)eta;  out[b * 6 + 4] = (float)phi;  out[b * 6 + 5] = (float)mass2;
    }
}

// ---------------------------------------------------------------------------
extern "C" void kernel_launch(void* const* d_in, const int* in_sizes, int n_in,
                              void* d_out, int out_size, void* d_ws, size_t ws_size,
                              hipStream_t stream)
{
    const float* xx    = (const float*)d_in[0];
    const float* emb1  = (const float*)d_in[1];
    const float* emb2  = (const float*)d_in[2];
    const float* emb3  = (const float*)d_in[3];
    const float* mean  = (const float*)d_in[4];
    const float* std_  = (const float*)d_in[5];
    const float* vmin  = (const float*)d_in[6];
    const float* vmax  = (const float*)d_in[7];
    const float* W0    = (const float*)d_in[8];
    const float* b0    = (const float*)d_in[9];
    const float* Wh    = (const float*)d_in[10];
    const float* bh    = (const float*)d_in[11];
    const float* gamma = (const float*)d_in[12];
    const float* beta  = (const float*)d_in[13];
    const float* mmean = (const float*)d_in[14];
    const float* mvar  = (const float*)d_in[15];
    const float* Wc    = (const float*)d_in[16];
    const float* bc    = (const float*)d_in[17];
    const float* W2    = (const float*)d_in[18];
    const float* b2    = (const float*)d_in[19];
    const float* W100  = (const float*)d_in[20];
    const float* b100  = (const float*)d_in[21];

    double* ws   = (double*)d_ws;
    double* x    = ws;                        // 128000
    double* gbuf = x + NB * NPF * FC;         // 440*32 = 14080 (k-major)
    double* Aa   = gbuf + 440 * MROWS;        // 115200 (k-major activations)
    double* Ab   = Aa + PSTRIDE;              // 115200
    double* act  = Ab + PSTRIDE;              // 115200
    double* P    = act + PSTRIDE;             // 17*115200 partial slots (~19.6 MB total)

    const size_t HS = (size_t)HH;

    pre_kernel<<<dim3(NB), dim3(256), 0, stream>>>(xx, emb1, emb2, emb3, mean, std_, vmin, vmax, x);

    for (int t = 0; t < NPF; ++t) {
        knn_kernel<<<dim3(NB), dim3(256), 0, stream>>>(x, act, Wc, bc, gbuf, (t == 0) ? 1 : 0);
        // L0: g^T[440][32] @ W0 -> P[0..15]
        gemm_kernel<<<dim3(15, SK0), dim3(256), 0, stream>>>(gbuf, W0, P, 440, KRC0);
        fix_kernel<<<dim3(450), dim3(256), 0, stream>>>(P, SK0, b0, gamma, beta, mmean, mvar, Aa);
        // L1..L4
        gemm_kernel<<<dim3(15, SKH), dim3(256), 0, stream>>>(Aa, Wh, P, HH, KRCH);
        fix_kernel<<<dim3(450), dim3(256), 0, stream>>>(P, SKH, bh, gamma + HS, beta + HS,
                                                        mmean + HS, mvar + HS, Ab);
        gemm_kernel<<<dim3(15, SKH), dim3(256), 0, stream>>>(Ab, Wh + HS * HS, P, HH, KRCH);
        fix_kernel<<<dim3(450), dim3(256), 0, stream>>>(P, SKH, bh + HS, gamma + 2 * HS, beta + 2 * HS,
                                                        mmean + 2 * HS, mvar + 2 * HS, Aa);
        gemm_kernel<<<dim3(15, SKH), dim3(256), 0, stream>>>(Aa, Wh + 2 * HS * HS, P, HH, KRCH);
        fix_kernel<<<dim3(450), dim3(256), 0, stream>>>(P, SKH, bh + 2 * HS, gamma + 3 * HS, beta + 3 * HS,
                                                        mmean + 3 * HS, mvar + 3 * HS, Ab);
        gemm_kernel<<<dim3(15, SKH), dim3(256), 0, stream>>>(Ab, Wh + 3 * HS * HS, P, HH, KRCH);
        fix_kernel<<<dim3(450), dim3(256), 0, stream>>>(P, SKH, bh + 3 * HS, gamma + 4 * HS, beta + 4 * HS,
                                                        mmean + 4 * HS, mvar + 4 * HS, act);
    }
    head_kernel<<<dim3(NB), dim3(256), 0, stream>>>(xx, act, W2, b2, W100, b100, (float*)d_out);
}